// Round 5
// baseline (72.683 us; speedup 1.0000x reference)
//
#include <hip/hip_runtime.h>
#include <math.h>

#define SIZE 128
#define BATCH 64
#define STEEP 10.0f
#define G 8      // layer-pairs per pipeline group
#define NG 8     // groups: 8*8 = 64 layer-pairs = 128 layers

// DPP lane move (verified R3/R4): 0x101=row_shl:1 (lane i <- i+1, 16-lane rows),
// 0x111=row_shr:1 (i <- i-1), 0x130=wave_shl:1, 0x138=wave_shr:1.
// bound_ctrl=false: invalid lanes keep old value (always masked or alpha=1-padded).
template<int CTRL>
__device__ __forceinline__ float dpp_mov(float x) {
    return __int_as_float(__builtin_amdgcn_update_dpp(
        __float_as_int(x), __float_as_int(x), CTRL, 0xf, 0xf, false));
}

// alpha = atan(STEEP*delta)/pi + 0.5. Estrin minimax poly (1/pi folded in),
// v_rcp range reduction, copysign fold. err ~1e-6 (absmax 3.9e-3 vs 3.6e-2
// threshold, validated R1-R4).
__device__ __forceinline__ float alpha_from_delta(float delta) {
    const float C0 =  0.31830265f;
    const float C1 = -0.10587730f;
    const float C2 =  0.06160680f;
    const float C3 = -0.03706173f;
    const float C4 =  0.01676007f;
    const float C5 = -0.00373098f;
    float t  = STEEP * delta;
    float at = fabsf(t);
    bool inv = at > 1.0f;
    float z  = inv ? __builtin_amdgcn_rcpf(at) : at;
    float z2 = z * z, z4 = z2 * z2;
    float p0 = fmaf(C1, z2, C0);
    float p1 = fmaf(C3, z2, C2);
    float p2 = fmaf(C5, z2, C4);
    float q  = fmaf(fmaf(p2, z4, p1), z4, p0) * z;
    float r  = inv ? 0.5f - q : q;
    return 0.5f + copysignf(r, t);
}

// One block = (batch, 16-row group). 192 threads = 3 waves; grid 512 -> 2
// blocks/CU for cross-block latency hiding.
// Wave 2 (producer): serial alpha chain, ping-pong LDS groups of G layer-
//   pairs; odd-layer pair 63 padded with alpha=1.0 (identity no-op).
// Waves 0-1 (consumers): each thread owns 2 rows x 8 contiguous cols of X in
//   registers (one alpha read feeds both rows); boundary exchange via DPP.
__global__ __launch_bounds__(192) void soft_sort_fused(
    const float* __restrict__ vec, float* __restrict__ out)
{
    __shared__ float alds[2][2 * G * 64];   // [buf][layer_in_group][pair]

    const int tid    = threadIdx.x;
    const int lane   = tid & 63;
    const int wave   = tid >> 6;
    const int batch  = blockIdx.x >> 3;
    const int rowgrp = blockIdx.x & 7;      // 8 groups of 16 rows

    if (wave == 2) {
        // ---------------- producer: serial alpha chain --------------------
        const int c0 = 2 * lane;
        const float2 xv = *reinterpret_cast<const float2*>(vec + batch * SIZE + c0);
        float xa = xv.x, xb = xv.y;
        const bool hasR = (lane < 63);
        const bool hasL = (lane > 0);

        for (int grp = 0; grp < NG; ++grp) {
            float* buf = &alds[grp & 1][0];
#pragma unroll
            for (int j = 0; j < G; ++j) {
                const float d  = xb - xa;
                const float ae = alpha_from_delta(d);
                buf[(2 * j) * 64 + lane] = ae;
                const float nxa0 = fmaf(-ae, d, xb);
                const float nxb0 = fmaf( ae, d, xa);
                const float xnext = dpp_mov<0x130>(nxa0);
                float ao = alpha_from_delta(xnext - nxb0);
                ao = hasR ? ao : 1.0f;                 // pad pair 63 -> identity
                buf[(2 * j + 1) * 64 + lane] = ao;
                float aoL = dpp_mov<0x138>(ao);
                aoL = hasL ? aoL : 1.0f;
                const float xprev = dpp_mov<0x138>(nxb0);
                xb = fmaf(ao,  nxb0 - xnext, xnext);
                xa = fmaf(aoL, nxa0 - xprev, xprev);
            }
            __syncthreads();   // release group grp
        }
        if (rowgrp == 0)
            *reinterpret_cast<float2*>(out + batch * SIZE + c0) = make_float2(xa, xb);
    } else {
        // ---------------- consumers: evolve 2 X rows per thread -----------
        const int chunk = lane & 15;            // cols 8*chunk .. 8*chunk+7
        const int rsub  = lane >> 4;            // 0..3
        const int row0  = rowgrp * 16 + wave * 8 + rsub * 2;
        const int row1  = row0 + 1;
        const int c8    = chunk * 8;
        const int q4    = chunk * 4;                      // even-pair base
        const int qm    = (chunk > 0) ? q4 - 1 : 63;      // left odd pair (63 = pad)

        float va[8], vb[8];
#pragma unroll
        for (int j = 0; j < 8; ++j) {
            va[j] = (row0 == c8 + j) ? 1.0f : 0.0f;
            vb[j] = (row1 == c8 + j) ? 1.0f : 0.0f;
        }

        for (int grp = 0; grp < NG; ++grp) {
            __syncthreads();   // wait for group grp
            const float* buf = &alds[grp & 1][0];
            float4 ae = *reinterpret_cast<const float4*>(buf + q4);
            float4 ao = *reinterpret_cast<const float4*>(buf + 64 + q4);
            float  aL = buf[64 + qm];
#pragma unroll
            for (int j = 0; j < G; ++j) {
                const int nj = (j < G - 1) ? j + 1 : j;
                const float4 ae_n = *reinterpret_cast<const float4*>(buf + (2 * nj) * 64 + q4);
                const float4 ao_n = *reinterpret_cast<const float4*>(buf + (2 * nj + 1) * 64 + q4);
                const float  aL_n = buf[(2 * nj + 1) * 64 + qm];

                float A, B, d;
                // even layer, row0: pairs (0,1)(2,3)(4,5)(6,7)
                A = va[0]; B = va[1]; d = A - B; va[0] = fmaf(ae.x, d, B); va[1] = fmaf(-ae.x, d, A);
                A = va[2]; B = va[3]; d = A - B; va[2] = fmaf(ae.y, d, B); va[3] = fmaf(-ae.y, d, A);
                A = va[4]; B = va[5]; d = A - B; va[4] = fmaf(ae.z, d, B); va[5] = fmaf(-ae.z, d, A);
                A = va[6]; B = va[7]; d = A - B; va[6] = fmaf(ae.w, d, B); va[7] = fmaf(-ae.w, d, A);
                // even layer, row1
                A = vb[0]; B = vb[1]; d = A - B; vb[0] = fmaf(ae.x, d, B); vb[1] = fmaf(-ae.x, d, A);
                A = vb[2]; B = vb[3]; d = A - B; vb[2] = fmaf(ae.y, d, B); vb[3] = fmaf(-ae.y, d, A);
                A = vb[4]; B = vb[5]; d = A - B; vb[4] = fmaf(ae.z, d, B); vb[5] = fmaf(-ae.z, d, A);
                A = vb[6]; B = vb[7]; d = A - B; vb[6] = fmaf(ae.w, d, B); vb[7] = fmaf(-ae.w, d, A);
                // boundary exchange (post-even; lanes lockstep within wave)
                const float nb0a = dpp_mov<0x101>(va[0]);
                const float pb7a = dpp_mov<0x111>(va[7]);
                const float nb0b = dpp_mov<0x101>(vb[0]);
                const float pb7b = dpp_mov<0x111>(vb[7]);
                // odd layer, row0: internal pairs (1,2)(3,4)(5,6)
                A = va[1]; B = va[2]; d = A - B; va[1] = fmaf(ao.x, d, B); va[2] = fmaf(-ao.x, d, A);
                A = va[3]; B = va[4]; d = A - B; va[3] = fmaf(ao.y, d, B); va[4] = fmaf(-ao.y, d, A);
                A = va[5]; B = va[6]; d = A - B; va[5] = fmaf(ao.z, d, B); va[6] = fmaf(-ao.z, d, A);
                // odd layer, row1
                A = vb[1]; B = vb[2]; d = A - B; vb[1] = fmaf(ao.x, d, B); vb[2] = fmaf(-ao.x, d, A);
                A = vb[3]; B = vb[4]; d = A - B; vb[3] = fmaf(ao.y, d, B); vb[4] = fmaf(-ao.y, d, A);
                A = vb[5]; B = vb[6]; d = A - B; vb[5] = fmaf(ao.z, d, B); vb[6] = fmaf(-ao.z, d, A);
                // boundary pairs; chunk edges see alpha==1.0 pad -> exact no-op
                va[7] = fmaf(ao.w, va[7] - nb0a, nb0a);
                va[0] = fmaf(aL,   va[0] - pb7a, pb7a);
                vb[7] = fmaf(ao.w, vb[7] - nb0b, nb0b);
                vb[0] = fmaf(aL,   vb[0] - pb7b, pb7b);

                ae = ae_n; ao = ao_n; aL = aL_n;
            }
        }

        float* __restrict__ X0 = out + BATCH * SIZE + (batch * SIZE + row0) * SIZE + c8;
        float* __restrict__ X1 = out + BATCH * SIZE + (batch * SIZE + row1) * SIZE + c8;
        *reinterpret_cast<float4*>(X0)     = make_float4(va[0], va[1], va[2], va[3]);
        *reinterpret_cast<float4*>(X0 + 4) = make_float4(va[4], va[5], va[6], va[7]);
        *reinterpret_cast<float4*>(X1)     = make_float4(vb[0], vb[1], vb[2], vb[3]);
        *reinterpret_cast<float4*>(X1 + 4) = make_float4(vb[4], vb[5], vb[6], vb[7]);
    }
}

extern "C" void kernel_launch(void* const* d_in, const int* in_sizes, int n_in,
                              void* d_out, int out_size, void* d_ws, size_t ws_size,
                              hipStream_t stream) {
    const float* vec = (const float*)d_in[0];
    float* out = (float*)d_out;
    (void)in_sizes; (void)n_in; (void)d_ws; (void)ws_size; (void)out_size;

    hipLaunchKernelGGL(soft_sort_fused, dim3(BATCH * 8), dim3(192), 0, stream,
                       vec, out);
}

// Round 6
// 68.405 us; speedup vs baseline: 1.0625x; 1.0625x over previous
//
#include <hip/hip_runtime.h>
#include <math.h>

#define SIZE 128
#define BATCH 64
#define STEEP 10.0f
#define G 8      // layer-pairs per pipeline group
#define NG 8     // groups: 8*8 = 64 layer-pairs = 128 layers

// DPP lane move (verified R3-R5): 0x101=row_shl:1 (lane i <- i+1, 16-lane rows),
// 0x111=row_shr:1 (i <- i-1), 0x130=wave_shl:1, 0x138=wave_shr:1.
// bound_ctrl=false: invalid lanes keep old value (masked or alpha=1-padded).
template<int CTRL>
__device__ __forceinline__ float dpp_mov(float x) {
    return __int_as_float(__builtin_amdgcn_update_dpp(
        __float_as_int(x), __float_as_int(x), CTRL, 0xf, 0xf, false));
}

// alpha = atan(STEEP*delta)/pi + 0.5. Estrin minimax poly (1/pi folded in),
// v_rcp range reduction, copysign fold. err ~1e-6 (absmax 3.9e-3 vs 3.6e-2
// threshold, validated R1-R5).
__device__ __forceinline__ float alpha_from_delta(float delta) {
    const float C0 =  0.31830265f;
    const float C1 = -0.10587730f;
    const float C2 =  0.06160680f;
    const float C3 = -0.03706173f;
    const float C4 =  0.01676007f;
    const float C5 = -0.00373098f;
    float t  = STEEP * delta;
    float at = fabsf(t);
    bool inv = at > 1.0f;
    float z  = inv ? __builtin_amdgcn_rcpf(at) : at;
    float z2 = z * z, z4 = z2 * z2;
    float p0 = fmaf(C1, z2, C0);
    float p1 = fmaf(C3, z2, C2);
    float p2 = fmaf(C5, z2, C4);
    float q  = fmaf(fmaf(p2, z4, p1), z4, p0) * z;
    float r  = inv ? 0.5f - q : q;
    return 0.5f + copysignf(r, t);
}

// One block = (batch, 32-row group). 320 threads = 5 waves; grid 256 ->
// 2+ blocks/CU for cross-block latency hiding, minimal chain replication
// (256 serial chains total, as in best-known R4).
// Wave 4 (producer): serial alpha chain, ping-pong LDS groups of G layer-
//   pairs; odd-layer pair 63 padded with alpha=1.0 (identity no-op).
// Waves 0-3 (consumers): each thread owns 2 rows x 8 contiguous cols of X
//   in registers (one alpha read feeds both rows); boundary via DPP.
__global__ __launch_bounds__(320) void soft_sort_fused(
    const float* __restrict__ vec, float* __restrict__ out)
{
    __shared__ float alds[2][2 * G * 64];   // [buf][layer_in_group][pair], 8 KB

    const int tid    = threadIdx.x;
    const int lane   = tid & 63;
    const int wave   = tid >> 6;
    const int batch  = blockIdx.x >> 2;
    const int rowgrp = blockIdx.x & 3;      // 4 groups of 32 rows

    if (wave == 4) {
        // ---------------- producer: serial alpha chain --------------------
        const int c0 = 2 * lane;
        const float2 xv = *reinterpret_cast<const float2*>(vec + batch * SIZE + c0);
        float xa = xv.x, xb = xv.y;
        const bool hasR = (lane < 63);
        const bool hasL = (lane > 0);

        for (int grp = 0; grp < NG; ++grp) {
            float* buf = &alds[grp & 1][0];
#pragma unroll
            for (int j = 0; j < G; ++j) {
                const float d  = xb - xa;
                const float ae = alpha_from_delta(d);
                buf[(2 * j) * 64 + lane] = ae;
                const float nxa0 = fmaf(-ae, d, xb);
                const float nxb0 = fmaf( ae, d, xa);
                const float xnext = dpp_mov<0x130>(nxa0);
                float ao = alpha_from_delta(xnext - nxb0);
                ao = hasR ? ao : 1.0f;                 // pad pair 63 -> identity
                buf[(2 * j + 1) * 64 + lane] = ao;
                float aoL = dpp_mov<0x138>(ao);
                aoL = hasL ? aoL : 1.0f;
                const float xprev = dpp_mov<0x138>(nxb0);
                xb = fmaf(ao,  nxb0 - xnext, xnext);
                xa = fmaf(aoL, nxa0 - xprev, xprev);
            }
            __syncthreads();   // release group grp
        }
        if (rowgrp == 0)
            *reinterpret_cast<float2*>(out + batch * SIZE + c0) = make_float2(xa, xb);
    } else {
        // ---------------- consumers: evolve 2 X rows per thread -----------
        const int chunk = lane & 15;            // cols 8*chunk .. 8*chunk+7
        const int rsub  = lane >> 4;            // 0..3
        const int row0  = rowgrp * 32 + wave * 8 + rsub * 2;
        const int row1  = row0 + 1;
        const int c8    = chunk * 8;
        const int q4    = chunk * 4;                      // even-pair base
        const int qm    = (chunk > 0) ? q4 - 1 : 63;      // left odd pair (63 = pad)

        float va[8], vb[8];
#pragma unroll
        for (int j = 0; j < 8; ++j) {
            va[j] = (row0 == c8 + j) ? 1.0f : 0.0f;
            vb[j] = (row1 == c8 + j) ? 1.0f : 0.0f;
        }

        for (int grp = 0; grp < NG; ++grp) {
            __syncthreads();   // wait for group grp
            const float* buf = &alds[grp & 1][0];
            float4 ae = *reinterpret_cast<const float4*>(buf + q4);
            float4 ao = *reinterpret_cast<const float4*>(buf + 64 + q4);
            float  aL = buf[64 + qm];
#pragma unroll
            for (int j = 0; j < G; ++j) {
                const int nj = (j < G - 1) ? j + 1 : j;
                const float4 ae_n = *reinterpret_cast<const float4*>(buf + (2 * nj) * 64 + q4);
                const float4 ao_n = *reinterpret_cast<const float4*>(buf + (2 * nj + 1) * 64 + q4);
                const float  aL_n = buf[(2 * nj + 1) * 64 + qm];

                float A, B, d;
                // even layer, row0: pairs (0,1)(2,3)(4,5)(6,7)
                A = va[0]; B = va[1]; d = A - B; va[0] = fmaf(ae.x, d, B); va[1] = fmaf(-ae.x, d, A);
                A = va[2]; B = va[3]; d = A - B; va[2] = fmaf(ae.y, d, B); va[3] = fmaf(-ae.y, d, A);
                A = va[4]; B = va[5]; d = A - B; va[4] = fmaf(ae.z, d, B); va[5] = fmaf(-ae.z, d, A);
                A = va[6]; B = va[7]; d = A - B; va[6] = fmaf(ae.w, d, B); va[7] = fmaf(-ae.w, d, A);
                // even layer, row1
                A = vb[0]; B = vb[1]; d = A - B; vb[0] = fmaf(ae.x, d, B); vb[1] = fmaf(-ae.x, d, A);
                A = vb[2]; B = vb[3]; d = A - B; vb[2] = fmaf(ae.y, d, B); vb[3] = fmaf(-ae.y, d, A);
                A = vb[4]; B = vb[5]; d = A - B; vb[4] = fmaf(ae.z, d, B); vb[5] = fmaf(-ae.z, d, A);
                A = vb[6]; B = vb[7]; d = A - B; vb[6] = fmaf(ae.w, d, B); vb[7] = fmaf(-ae.w, d, A);
                // boundary exchange (post-even; lanes lockstep within wave)
                const float nb0a = dpp_mov<0x101>(va[0]);
                const float pb7a = dpp_mov<0x111>(va[7]);
                const float nb0b = dpp_mov<0x101>(vb[0]);
                const float pb7b = dpp_mov<0x111>(vb[7]);
                // odd layer, row0: internal pairs (1,2)(3,4)(5,6)
                A = va[1]; B = va[2]; d = A - B; va[1] = fmaf(ao.x, d, B); va[2] = fmaf(-ao.x, d, A);
                A = va[3]; B = va[4]; d = A - B; va[3] = fmaf(ao.y, d, B); va[4] = fmaf(-ao.y, d, A);
                A = va[5]; B = va[6]; d = A - B; va[5] = fmaf(ao.z, d, B); va[6] = fmaf(-ao.z, d, A);
                // odd layer, row1
                A = vb[1]; B = vb[2]; d = A - B; vb[1] = fmaf(ao.x, d, B); vb[2] = fmaf(-ao.x, d, A);
                A = vb[3]; B = vb[4]; d = A - B; vb[3] = fmaf(ao.y, d, B); vb[4] = fmaf(-ao.y, d, A);
                A = vb[5]; B = vb[6]; d = A - B; vb[5] = fmaf(ao.z, d, B); vb[6] = fmaf(-ao.z, d, A);
                // boundary pairs; chunk edges see alpha==1.0 pad -> exact no-op
                va[7] = fmaf(ao.w, va[7] - nb0a, nb0a);
                va[0] = fmaf(aL,   va[0] - pb7a, pb7a);
                vb[7] = fmaf(ao.w, vb[7] - nb0b, nb0b);
                vb[0] = fmaf(aL,   vb[0] - pb7b, pb7b);

                ae = ae_n; ao = ao_n; aL = aL_n;
            }
        }

        float* __restrict__ X0 = out + BATCH * SIZE + (batch * SIZE + row0) * SIZE + c8;
        float* __restrict__ X1 = out + BATCH * SIZE + (batch * SIZE + row1) * SIZE + c8;
        *reinterpret_cast<float4*>(X0)     = make_float4(va[0], va[1], va[2], va[3]);
        *reinterpret_cast<float4*>(X0 + 4) = make_float4(va[4], va[5], va[6], va[7]);
        *reinterpret_cast<float4*>(X1)     = make_float4(vb[0], vb[1], vb[2], vb[3]);
        *reinterpret_cast<float4*>(X1 + 4) = make_float4(vb[4], vb[5], vb[6], vb[7]);
    }
}

extern "C" void kernel_launch(void* const* d_in, const int* in_sizes, int n_in,
                              void* d_out, int out_size, void* d_ws, size_t ws_size,
                              hipStream_t stream) {
    const float* vec = (const float*)d_in[0];
    float* out = (float*)d_out;
    (void)in_sizes; (void)n_in; (void)d_ws; (void)ws_size; (void)out_size;

    hipLaunchKernelGGL(soft_sort_fused, dim3(BATCH * 4), dim3(320), 0, stream,
                       vec, out);
}